// Round 5
// baseline (386.683 us; speedup 1.0000x reference)
//
#include <hip/hip_runtime.h>
#include <hip/hip_bf16.h>
#include <math.h>

#define B_  4
#define S_  2048
#define D_  1024
#define H_  16
#define HD_ 64
#define SD_  (S_*D_)        // 2097152
#define SHD_ (S_*HD_)       // 131072

typedef __attribute__((ext_vector_type(8))) short          bf16x8;   // MFMA A/B frag (4 VGPRs)
typedef __attribute__((ext_vector_type(4))) float          f32x4;    // MFMA C/D frag
typedef __attribute__((ext_vector_type(8))) unsigned short us8;
typedef __attribute__((ext_vector_type(4))) unsigned short us4;

__device__ __forceinline__ unsigned short f2bf(float x) {  // RNE float->bf16
  unsigned int u = __float_as_uint(x);
  u += 0x7fffu + ((u >> 16) & 1u);
  return (unsigned short)(u >> 16);
}
__device__ __forceinline__ float bf2f(unsigned short u) {
  return __uint_as_float(((unsigned int)u) << 16);
}

// async global->LDS, 16B per lane: wave-uniform LDS base + lane*16 (m104).
__device__ __forceinline__ void gload16(const unsigned short* g, unsigned short* l) {
  __builtin_amdgcn_global_load_lds(
      (const __attribute__((address_space(1))) unsigned int*)g,
      (__attribute__((address_space(3))) unsigned int*)l,
      16, 0, 0);
}

// ---------------------------------------------------------------------------
// Stage a 64-row x 128-byte tile global->LDS with XOR-swizzled SOURCE, so
// that swizzled ds_reads (byte ^= (row&7)<<4) observe linear global data.
// ---------------------------------------------------------------------------
__device__ __forceinline__ void stage_swz(const unsigned short* __restrict__ g,
                                          int rstride /*elems*/,
                                          unsigned short* lds, int tid)
{
#pragma unroll
  for (int rr = 0; rr < 2; ++rr) {
    const int cidx = tid + rr * 256;               // 16B chunk index 0..511
    const int row  = cidx >> 3;                    // 0..63
    const int sb   = ((cidx & 7) * 16) ^ ((row & 7) << 4);  // swizzled src byte
    gload16(g + (size_t)row * rstride + (sb >> 1), lds + cidx * 8);
  }
}

// read one MFMA frag pair (cols [0,64) and [64,128) bytes of a tile row)
// from a swizzle-stored LDS tile.
__device__ __forceinline__ void read_frag_pair(const unsigned short* lds, int row,
                                               int quad, bf16x8& f0, bf16x8& f1)
{
  const int sw = (row & 7) << 4;
  const unsigned short* p = lds + row * 64;
  f0 = *(const bf16x8*)(p + (((quad * 16) ^ sw) >> 1));
  f1 = *(const bf16x8*)(p + (((64 + quad * 16) ^ sw) >> 1));
}

// ---------------------------------------------------------------------------
// merged small converts: weights (4096 WGs) + pad mask (8 WGs)
// ---------------------------------------------------------------------------
__global__ __launch_bounds__(256) void cvt_wp(
    const float* __restrict__ w0, const float* __restrict__ w1,
    const float* __restrict__ w2, const float* __restrict__ w3,
    const int* __restrict__ pad,
    unsigned short* __restrict__ Wall, float* __restrict__ padf)
{
  const int bx = blockIdx.x;
  if (bx < 4096) {
    const int y = bx >> 10;                       // 0..3
    const int i = (bx & 1023) * 256 + threadIdx.x;
    const float* s = (y == 0) ? w0 : (y == 1) ? w1 : (y == 2) ? w2 : w3;
    unsigned short* d = Wall + (size_t)y * 1024 * 1024;
    float4 x = ((const float4*)s)[i];
    us4 o = { f2bf(x.x), f2bf(x.y), f2bf(x.z), f2bf(x.w) };
    *(us4*)(d + (size_t)i * 4) = o;
  } else {
    const int i = ((bx - 4096) * 256 + threadIdx.x) * 4;   // 8192 ints total
    int4 pv = *(const int4*)(pad + i);
    float4 o = { pv.x ? 0.f : -1e30f, pv.y ? 0.f : -1e30f,
                 pv.z ? 0.f : -1e30f, pv.w ? 0.f : -1e30f };
    *(float4*)(padf + i) = o;
  }
}

// bijective XCD swizzle over the (x,y) grid plane: nwg = 512 (%8==0)
__device__ __forceinline__ void xcd_coords(int& n0, int& m0)
{
  const int nwgx = gridDim.x;
  const int nwg  = nwgx * gridDim.y;
  const int bid  = blockIdx.y * nwgx + blockIdx.x;
  const int sw   = (bid & 7) * (nwg >> 3) + (bid >> 3);
  n0 = (sw % nwgx) * 128;
  m0 = (sw / nwgx) * 128;
}

// shared GEMM epilogue: C-layout col=l16, row=quad*4+reg (m89-verified)
__device__ __forceinline__ void gemm_epilogue(
    f32x4 (&acc)[4][4], const float* __restrict__ bias,
    unsigned short* __restrict__ Cb, int n0, int m0,
    int wm, int wn, int l16, int quad)
{
#pragma unroll
  for (int nt = 0; nt < 4; ++nt) {
    const int ncol = n0 + wn * 64 + nt * 16 + l16;
    const float bv = bias[ncol];
#pragma unroll
    for (int mt = 0; mt < 4; ++mt) {
      const int row = m0 + wm * 64 + mt * 16 + quad * 4;
#pragma unroll
      for (int reg = 0; reg < 4; ++reg)
        Cb[(size_t)(row + reg) * 1024 + ncol] = f2bf(acc[mt][nt][reg] + bv);
    }
  }
}

__device__ __forceinline__ void store_bf8(unsigned short* p, float4 a, float4 b)
{
  us8 o = { f2bf(a.x), f2bf(a.y), f2bf(a.z), f2bf(a.w),
            f2bf(b.x), f2bf(b.y), f2bf(b.z), f2bf(b.w) };
  *(us8*)p = o;
}

// ---------------------------------------------------------------------------
// Fused cvt+QKV GEMM: reads fp32 activations DIRECTLY (reg-staged A side:
// float4 loads -> f2bf -> ds_write), W side via global_load_lds. Removes the
// separate 144 MB fp32->bf16 conversion pass. Minimal 2-phase pipeline
// (T3-min): one __syncthreads per K-step; stage kt+1 issued before compute so
// its latency flies under the MFMA phase.
// C[8192,1024] = A_f32 @ W^T + bias, bf16 out. 128x128 tile, BK=32, 4 waves.
// ---------------------------------------------------------------------------
__global__ __launch_bounds__(256) void gemm_qkv_f32(
    const float* __restrict__ qf, const float* __restrict__ kf,
    const float* __restrict__ vf,
    const unsigned short* __restrict__ Wall,
    const float* __restrict__ bq, const float* __restrict__ bk,
    const float* __restrict__ bv,
    unsigned short* __restrict__ Qb, unsigned short* __restrict__ Kb,
    unsigned short* __restrict__ Vb)
{
  __shared__ unsigned short As[2][128 * 32];   // 2 x 8 KB
  __shared__ unsigned short Bs[2][128 * 32];   // 2 x 8 KB

  const int z = blockIdx.z;
  const float* Af = (z == 0) ? qf : (z == 1) ? kf : vf;
  const unsigned short* Wb = Wall + (size_t)z * 1024 * 1024;
  const float* bias = (z == 0) ? bq : (z == 1) ? bk : bv;
  unsigned short* Cb = (z == 0) ? Qb : (z == 1) ? Kb : Vb;

  int n0, m0;
  xcd_coords(n0, m0);

  const int tid  = threadIdx.x;
  const int lane = tid & 63;
  const int w    = tid >> 6;
  const int wm   = w >> 1, wn = w & 1;
  const int l16  = lane & 15, quad = lane >> 4;

  f32x4 acc[4][4];
#pragma unroll
  for (int mt = 0; mt < 4; ++mt)
#pragma unroll
    for (int nt = 0; nt < 4; ++nt) acc[mt][nt] = (f32x4){0.f, 0.f, 0.f, 0.f};

  const int srow = lane >> 2;          // 0..15
  const int sseg = (lane & 3) * 8;     // elem offset within 32-elem row
  const int r0   = w * 32 + srow, r1 = r0 + 16;

  const float* A0 = Af + (size_t)(m0 + r0) * 1024 + sseg;
  const float* A1 = Af + (size_t)(m0 + r1) * 1024 + sseg;
  const unsigned short* B0 = Wb + (size_t)(n0 + r0) * 1024 + sseg;
  const unsigned short* B1 = Wb + (size_t)(n0 + r1) * 1024 + sseg;
  unsigned short* dA0 = &As[0][r0 * 32 + sseg];   // [buf] via +4096 stride
  unsigned short* dB0 = &Bs[0][r0 * 32 + sseg];

  // ---- prologue: tile 0 ----
  {
    float4 f0 = *(const float4*)(A0),     f1 = *(const float4*)(A0 + 4);
    float4 f2 = *(const float4*)(A1),     f3 = *(const float4*)(A1 + 4);
    gload16(B0, dB0);
    gload16(B1, dB0 + 16 * 32);
    store_bf8(dA0,           f0, f1);
    store_bf8(dA0 + 16 * 32, f2, f3);
  }

  int buf = 0;
  for (int kt = 0; kt < 32; ++kt) {
    __syncthreads();   // tile kt fully landed (vmcnt + lgkm drain)

    float4 f0, f1, f2, f3;
    if (kt < 31) {     // issue next tile: A f32 loads first (older), then W DMA
      const int ko = (kt + 1) * 32;
      f0 = *(const float4*)(A0 + ko);  f1 = *(const float4*)(A0 + ko + 4);
      f2 = *(const float4*)(A1 + ko);  f3 = *(const float4*)(A1 + ko + 4);
      const int nb = (buf ^ 1) * 4096;
      gload16(B0 + ko, dB0 + nb);
      gload16(B1 + ko, dB0 + nb + 16 * 32);
    }

    // ---- compute tile kt ----
    const unsigned short* Ab = As[buf];
    const unsigned short* Bb = Bs[buf];
    bf16x8 af[4], bfr[4];
#pragma unroll
    for (int mt = 0; mt < 4; ++mt)
      af[mt] = *(const bf16x8*)&Ab[(wm * 64 + mt * 16 + l16) * 32 + quad * 8];
#pragma unroll
    for (int nt = 0; nt < 4; ++nt)
      bfr[nt] = *(const bf16x8*)&Bb[(wn * 64 + nt * 16 + l16) * 32 + quad * 8];
#pragma unroll
    for (int mt = 0; mt < 4; ++mt)
#pragma unroll
      for (int nt = 0; nt < 4; ++nt)
        acc[mt][nt] = __builtin_amdgcn_mfma_f32_16x16x32_bf16(
            af[mt], bfr[nt], acc[mt][nt], 0, 0, 0);

    if (kt < 31) {     // write-late: cvt + ds_write next A tile
      const int nb = (buf ^ 1) * 4096;
      store_bf8(dA0 + nb,           f0, f1);
      store_bf8(dA0 + nb + 16 * 32, f2, f3);
      buf ^= 1;
    }
  }

  gemm_epilogue(acc, bias, Cb, n0, m0, wm, wn, l16, quad);
}

// ---------------------------------------------------------------------------
// Wo GEMM: bf16 A (attn output), both sides global_load_lds; same minimal
// 2-phase single-barrier loop.
// ---------------------------------------------------------------------------
__global__ __launch_bounds__(256) void gemm_mfma(
    const unsigned short* __restrict__ A, const unsigned short* __restrict__ Wb,
    const float* __restrict__ bias, unsigned short* __restrict__ Cb)
{
  __shared__ unsigned short As[2][128 * 32];
  __shared__ unsigned short Bs[2][128 * 32];

  int n0, m0;
  xcd_coords(n0, m0);

  const int tid  = threadIdx.x;
  const int lane = tid & 63;
  const int w    = tid >> 6;
  const int wm   = w >> 1, wn = w & 1;
  const int l16  = lane & 15, quad = lane >> 4;

  f32x4 acc[4][4];
#pragma unroll
  for (int mt = 0; mt < 4; ++mt)
#pragma unroll
    for (int nt = 0; nt < 4; ++nt) acc[mt][nt] = (f32x4){0.f, 0.f, 0.f, 0.f};

  const int srow = lane >> 2;
  const int sseg = (lane & 3) * 8;
  const int r0   = w * 32 + srow, r1 = r0 + 16;

  const unsigned short* A0 = A  + (size_t)(m0 + r0) * 1024 + sseg;
  const unsigned short* A1 = A  + (size_t)(m0 + r1) * 1024 + sseg;
  const unsigned short* B0 = Wb + (size_t)(n0 + r0) * 1024 + sseg;
  const unsigned short* B1 = Wb + (size_t)(n0 + r1) * 1024 + sseg;
  unsigned short* dA0 = &As[0][r0 * 32 + sseg];
  unsigned short* dB0 = &Bs[0][r0 * 32 + sseg];

  // prologue
  gload16(A0, dA0);            gload16(A1, dA0 + 16 * 32);
  gload16(B0, dB0);            gload16(B1, dB0 + 16 * 32);

  int buf = 0;
  for (int kt = 0; kt < 32; ++kt) {
    __syncthreads();

    if (kt < 31) {
      const int ko = (kt + 1) * 32;
      const int nb = (buf ^ 1) * 4096;
      gload16(A0 + ko, dA0 + nb);  gload16(A1 + ko, dA0 + nb + 16 * 32);
      gload16(B0 + ko, dB0 + nb);  gload16(B1 + ko, dB0 + nb + 16 * 32);
    }

    const unsigned short* Ab = As[buf];
    const unsigned short* Bb = Bs[buf];
    bf16x8 af[4], bfr[4];
#pragma unroll
    for (int mt = 0; mt < 4; ++mt)
      af[mt] = *(const bf16x8*)&Ab[(wm * 64 + mt * 16 + l16) * 32 + quad * 8];
#pragma unroll
    for (int nt = 0; nt < 4; ++nt)
      bfr[nt] = *(const bf16x8*)&Bb[(wn * 64 + nt * 16 + l16) * 32 + quad * 8];
#pragma unroll
    for (int mt = 0; mt < 4; ++mt)
#pragma unroll
      for (int nt = 0; nt < 4; ++nt)
        acc[mt][nt] = __builtin_amdgcn_mfma_f32_16x16x32_bf16(
            af[mt], bfr[nt], acc[mt][nt], 0, 0, 0);

    buf ^= 1;
  }

  gemm_epilogue(acc, bias, Cb, n0, m0, wm, wn, l16, quad);
}

// ---------------------------------------------------------------------------
// V transpose: Vt[bh][d][s] = Vflat[bh*131072 + s*64 + d]
// ---------------------------------------------------------------------------
__global__ __launch_bounds__(256) void vtrans(
    const unsigned short* __restrict__ V, unsigned short* __restrict__ Vt)
{
  __shared__ unsigned short t[64][72];   // t[s][d], padded rows
  const int tid = threadIdx.x;
  const int st  = blockIdx.x;            // s-tile 0..31
  const int bh  = blockIdx.y;            // 0..63
  const unsigned short* src = V + (size_t)bh * SHD_ + (size_t)st * 4096;

#pragma unroll
  for (int u = tid; u < 512; u += 256) {           // 512 us8 chunks = 8 KB
    us8 vv = ((const us8*)src)[u];
    int s  = u >> 3;
    int dg = (u & 7) * 8;
    *(us8*)&t[s][dg] = vv;
  }
  __syncthreads();

  unsigned short* dst = Vt + (size_t)bh * SHD_ + st * 64;
#pragma unroll
  for (int u = tid; u < 1024; u += 256) {          // 64 d-rows x 16 us4 chunks
    int d  = u >> 4;
    int s4 = (u & 15) * 4;
    us4 o = { t[s4][d], t[s4 + 1][d], t[s4 + 2][d], t[s4 + 3][d] };
    *(us4*)(dst + (size_t)d * 2048 + s4) = o;
  }
}

// ---------------------------------------------------------------------------
// MFMA flash attention: diagonal pairing + LDS-staged K/V + swapped-QK softmax
// + XCD-PINNED bh MAPPING + defer-rescale (T13).
// XCD pin: linear WG id -> xcd = id&7; bh = (id&7) + 8*((id>>3)&7); p = id>>6.
// All 16 p-blocks of a bh land on ONE XCD -> per-XCD K/V working set = 8 bh
// x 512 KB = 4 MB = one L2. Round-3 counters showed 265 MB FETCH (8 XCDs each
// refetching every bh's K/V through L3); ideal is ~65 MB.
// T13: skip the alpha broadcast + O rescale when __all(mx <= mS + 8): P is
// then bounded by e^8 (bf16-safe), l,O accumulate unscaled (f32-safe).
// ---------------------------------------------------------------------------
__global__ __launch_bounds__(256, 4) void attn_mfma(
    unsigned short* __restrict__ Qb, const unsigned short* __restrict__ Kb,
    const unsigned short* __restrict__ Vt, const float* __restrict__ padf)
{
  __shared__ unsigned short Ks[64 * 64];        // 8 KB, single-buffered
  __shared__ unsigned short Vs[2][64 * 64];     // 16 KB, double-buffered
  __shared__ unsigned short Ps[4][16][72];      // per-wave P strip, 9 KB

  const int tid  = threadIdx.x;
  const int lane = tid & 63;
  const int w    = tid >> 6;
  const int id   = blockIdx.y * 16 + blockIdx.x;
  const int p    = id >> 6;                          // 0..15
  const int bh   = (id & 7) + 8 * ((id >> 3) & 7);   // 0..63, xcd = bh&7
  const int b    = bh >> 4;
  const size_t base = (size_t)bh * SHD_;

  const int l16  = lane & 15;
  const int quad = lane >> 4;

  for (int half = 0; half < 2; ++half) {
    const int it = half ? (31 - p) : p;

    bf16x8 qfrag[2];   // Q rows w*16+l16 -> B operand (columns q)
    {
      const unsigned short* qrow = Qb + base + (size_t)(it * 64 + w * 16 + l16) * 64;
      qfrag[0] = *(const bf16x8*)(qrow + quad * 8);
      qfrag[1] = *(const bf16x8*)(qrow + 32 + quad * 8);
    }

    f32x4 oacc[4];
#pragma unroll
    for (int dt = 0; dt < 4; ++dt) oacc[dt] = (f32x4){0.f, 0.f, 0.f, 0.f};
    float mS = -INFINITY, lS = 0.f;   // softmax state for q = it*64+w*16+l16

    // ---- half prologue: protect LDS from previous half, stage tile 0 ----
    __syncthreads();
    stage_swz(Kb + base, 64, Ks, tid);
    stage_swz(Vt + base, 2048, Vs[0], tid);
    float4 pf[4];
#pragma unroll
    for (int ct = 0; ct < 4; ++ct)
      pf[ct] = *(const float4*)(padf + b * S_ + ct * 16 + quad * 4);
    int cur = 0;

    for (int jt = 0; jt <= it; ++jt) {
      __syncthreads();   // barrier-1: staged K/V(jt) landed (vmcnt drain)

      // ---- QK^T swapped: A = K rows (ct tiles), B = Q ----
      f32x4 sacc[4];
#pragma unroll
      for (int ct = 0; ct < 4; ++ct) {
        bf16x8 k0, k1;
        read_frag_pair(Ks, ct * 16 + l16, quad, k0, k1);
        f32x4 s = (f32x4){0.f, 0.f, 0.f, 0.f};
        s = __builtin_amdgcn_mfma_f32_16x16x32_bf16(k0, qfrag[0], s, 0, 0, 0);
        s = __builtin_amdgcn_mfma_f32_16x16x32_bf16(k1, qfrag[1], s, 0, 0, 0);
        sacc[ct] = s;   // D[k=quad*4+reg (+ct*16)][q=l16]
      }

      // ---- barrier-2 + next-tile stage (hides under softmax+PV) ----
      float4 pfn[4];
      if (jt < it) {
        __syncthreads();   // all waves' K ds_reads complete -> Ks reusable
        stage_swz(Kb + base + (size_t)(jt + 1) * 4096, 64, Ks, tid);
        stage_swz(Vt + base + (jt + 1) * 64, 2048, Vs[cur ^ 1], tid);
#pragma unroll
        for (int ct = 0; ct < 4; ++ct)
          pfn[ct] = *(const float4*)(padf + b * S_ + (jt + 1) * 64 + ct * 16 + quad * 4);
      }

      // ---- swapped softmax: per-lane reduce over 16 regs + 2 shfl_xor ----
      float lg[4][4];
      float mx = -INFINITY;
#pragma unroll
      for (int ct = 0; ct < 4; ++ct)
#pragma unroll
        for (int reg = 0; reg < 4; ++reg) {
          float sc = fmaf(sacc[ct][reg], 0.125f, ((const float*)&pf[ct])[reg]);
          if (jt == it) {   // causal only needed on the diagonal tile
            bool ok = (ct * 16 + quad * 4 + reg) <= (w * 16 + l16);
            sc = ok ? sc : -1e30f;
          }
          lg[ct][reg] = sc;
          mx = fmaxf(mx, sc);
        }
      mx = fmaxf(mx, __shfl_xor(mx, 16, 64));
      mx = fmaxf(mx, __shfl_xor(mx, 32, 64));

      // ---- T13 defer-rescale: only rescale when the max actually grows ----
      if (!__all(mx <= mS + 8.f)) {
        const float mnew = fmaxf(mS, mx);
        const float a    = __expf(mS - mnew);
        mS = mnew;
        lS *= a;
        float aO[4];
#pragma unroll
        for (int reg = 0; reg < 4; ++reg) aO[reg] = __shfl(a, quad * 4 + reg, 64);
#pragma unroll
        for (int dt = 0; dt < 4; ++dt)
#pragma unroll
          for (int reg = 0; reg < 4; ++reg) oacc[dt][reg] *= aO[reg];
      }

      float sm = 0.f;
#pragma unroll
      for (int ct = 0; ct < 4; ++ct) {
        us4 pk;
#pragma unroll
        for (int reg = 0; reg < 4; ++reg) {
          float pe = __expf(lg[ct][reg] - mS);
          sm += pe;
          pk[reg] = f2bf(pe);
        }
        *(us4*)&Ps[w][l16][ct * 16 + quad * 4] = pk;   // P[q=l16][k contig]
      }
      sm += __shfl_xor(sm, 16, 64);
      sm += __shfl_xor(sm, 32, 64);
      lS += sm;

      // ---- PV: A-frag = P rows (LDS strip), B-frags = V^T rows from LDS ----
      bf16x8 pfrag0 = *(const bf16x8*)&Ps[w][l16][quad * 8];
      bf16x8 pfrag1 = *(const bf16x8*)&Ps[w][l16][32 + quad * 8];
#pragma unroll
      for (int dt = 0; dt < 4; ++dt) {
        bf16x8 v0, v1;
        read_frag_pair(Vs[cur], dt * 16 + l16, quad, v0, v1);
        oacc[dt] = __builtin_amdgcn_mfma_f32_16x16x32_bf16(pfrag0, v0, oacc[dt], 0, 0, 0);
        oacc[dt] = __builtin_amdgcn_mfma_f32_16x16x32_bf16(pfrag1, v1, oacc[dt], 0, 0, 0);
      }

      if (jt < it) {
#pragma unroll
        for (int ct = 0; ct < 4; ++ct) pf[ct] = pfn[ct];
        cur ^= 1;
      }
    }

    // epilogue: l back to O layout, normalize, write bf16 in place over Qb
    float lO[4];
#pragma unroll
    for (int reg = 0; reg < 4; ++reg) lO[reg] = __shfl(lS, quad * 4 + reg, 64);
#pragma unroll
    for (int reg = 0; reg < 4; ++reg) {
      const float rl = 1.0f / lO[reg];
      unsigned short* orow = Qb + base + (size_t)(it * 64 + w * 16 + quad * 4 + reg) * 64;
#pragma unroll
      for (int dt = 0; dt < 4; ++dt)
        orow[dt * 16 + l16] = f2bf(oacc[dt][reg] * rl);
    }
  }
}

// ---------------------------------------------------------------------------
// Residual + LayerNorm; O is bf16.
// ---------------------------------------------------------------------------
__global__ __launch_bounds__(256) void ln_kernel(
    const float* __restrict__ x, const unsigned short* __restrict__ O,
    const float* __restrict__ gamma, const float* __restrict__ beta,
    float* __restrict__ out)
{
  __shared__ float red[8];
  const int row = blockIdx.x;
  const int tid = threadIdx.x;
  float4 xv = ((const float4*)x)[(size_t)row * 256 + tid];
  us4 ov4 = *(const us4*)(O + (size_t)row * 1024 + tid * 4);
  float4 y = make_float4(xv.x + bf2f(ov4[0]), xv.y + bf2f(ov4[1]),
                         xv.z + bf2f(ov4[2]), xv.w + bf2f(ov4[3]));
  float s1 = y.x + y.y + y.z + y.w;
  float s2 = y.x*y.x + y.y*y.y + y.z*y.z + y.w*y.w;
#pragma unroll
  for (int off = 32; off >= 1; off >>= 1) {
    s1 += __shfl_xor(s1, off, 64);
    s2 += __shfl_xor(s2, off, 64);
  }
  if ((tid & 63) == 0) { red[tid >> 6] = s1; red[4 + (tid >> 6)] = s2; }
  __syncthreads();
  s1 = red[0] + red[1] + red[2] + red[3];
  s2 = red[4] + red[5] + red[6] + red[7];
  const float mean = s1 * (1.0f / 1024.0f);
  const float var  = fmaxf(s2 * (1.0f / 1024.0f) - mean * mean, 0.f);
  const float rstd = 1.0f / (sqrtf(var) + 1e-8f);
  float4 gv = ((const float4*)gamma)[tid];
  float4 bv = ((const float4*)beta)[tid];
  float4 r;
  r.x = gv.x * (y.x - mean) * rstd + bv.x;
  r.y = gv.y * (y.y - mean) * rstd + bv.y;
  r.z = gv.z * (y.z - mean) * rstd + bv.z;
  r.w = gv.w * (y.w - mean) * rstd + bv.w;
  ((float4*)out)[(size_t)row * 256 + tid] = r;
}

// ---------------------------------------------------------------------------
extern "C" void kernel_launch(void* const* d_in, const int* in_sizes, int n_in,
                              void* d_out, int out_size, void* d_ws, size_t ws_size,
                              hipStream_t stream)
{
  const float* q  = (const float*)d_in[0];
  const float* k  = (const float*)d_in[1];
  const float* v  = (const float*)d_in[2];
  // d_in[3] = causal tril mask — applied analytically (j<=i)
  const int*   pad = (const int*)d_in[4];
  const float* Wq = (const float*)d_in[5];
  const float* bq = (const float*)d_in[6];
  const float* Wk = (const float*)d_in[7];
  const float* bk = (const float*)d_in[8];
  const float* Wv = (const float*)d_in[9];
  const float* bv = (const float*)d_in[10];
  const float* Wo = (const float*)d_in[11];
  const float* bo = (const float*)d_in[12];
  const float* gamma = (const float*)d_in[13];
  const float* beta  = (const float*)d_in[14];
  float* out = (float*)d_out;

  char* ws = (char*)d_ws;
  const size_t MB = 1024 * 1024;
  unsigned short* Qb   = (unsigned short*)(ws);             // 16 MB
  unsigned short* Kb   = (unsigned short*)(ws + 16 * MB);   // 16 MB
  unsigned short* Vb   = (unsigned short*)(ws + 32 * MB);   // 16 MB
  unsigned short* Vtb  = (unsigned short*)(ws + 48 * MB);   // 16 MB
  unsigned short* Obuf = (unsigned short*)(ws + 64 * MB);   // 16 MB
  unsigned short* Wall = (unsigned short*)(ws + 80 * MB);   // 8 MB
  float*          padf = (float*)(ws + 88 * MB);            // 32 KB

  dim3 gg(8, 64), bb(256);

  cvt_wp<<<dim3(4104), 256, 0, stream>>>(Wq, Wk, Wv, Wo, pad, Wall, padf);
  gemm_qkv_f32<<<dim3(8, 64, 3), bb, 0, stream>>>(q, k, v, Wall, bq, bk, bv,
                                                  Qb, Kb, Vb);
  vtrans<<<dim3(32, 64), 256, 0, stream>>>(Vb, Vtb);
  attn_mfma<<<dim3(16, 64), 256, 0, stream>>>(Qb, Kb, Vtb, padf);
  gemm_mfma<<<gg, bb, 0, stream>>>(Qb, Wall + 3 * MB, bo, Obuf);
  ln_kernel<<<dim3(B_ * S_), 256, 0, stream>>>(q, Obuf, gamma, beta, out);
}

// Round 6
// 366.264 us; speedup vs baseline: 1.0558x; 1.0558x over previous
//
#include <hip/hip_runtime.h>
#include <hip/hip_bf16.h>
#include <math.h>

#define B_  4
#define S_  2048
#define D_  1024
#define H_  16
#define HD_ 64
#define SD_  (S_*D_)        // 2097152
#define SHD_ (S_*HD_)       // 131072

typedef __attribute__((ext_vector_type(8))) short          bf16x8;   // MFMA A/B frag (4 VGPRs)
typedef __attribute__((ext_vector_type(4))) float          f32x4;    // MFMA C/D frag
typedef __attribute__((ext_vector_type(8))) unsigned short us8;
typedef __attribute__((ext_vector_type(4))) unsigned short us4;

__device__ __forceinline__ unsigned short f2bf(float x) {  // RNE float->bf16
  unsigned int u = __float_as_uint(x);
  u += 0x7fffu + ((u >> 16) & 1u);
  return (unsigned short)(u >> 16);
}
__device__ __forceinline__ float bf2f(unsigned short u) {
  return __uint_as_float(((unsigned int)u) << 16);
}

// async global->LDS, 16B per lane: wave-uniform LDS base + lane*16 (m104).
__device__ __forceinline__ void gload16(const unsigned short* g, unsigned short* l) {
  __builtin_amdgcn_global_load_lds(
      (const __attribute__((address_space(1))) unsigned int*)g,
      (__attribute__((address_space(3))) unsigned int*)l,
      16, 0, 0);
}

// ---------------------------------------------------------------------------
// 64B-row tile swizzle (attn K/V tiles): byte ^= (row&7)<<4 within 128B rows.
// ---------------------------------------------------------------------------
__device__ __forceinline__ void stage_swz(const unsigned short* __restrict__ g,
                                          int rstride /*elems*/,
                                          unsigned short* lds, int tid)
{
#pragma unroll
  for (int rr = 0; rr < 2; ++rr) {
    const int cidx = tid + rr * 256;               // 16B chunk index 0..511
    const int row  = cidx >> 3;                    // 0..63
    const int sb   = ((cidx & 7) * 16) ^ ((row & 7) << 4);  // swizzled src byte
    gload16(g + (size_t)row * rstride + (sb >> 1), lds + cidx * 8);
  }
}

__device__ __forceinline__ void read_frag_pair(const unsigned short* lds, int row,
                                               int quad, bf16x8& f0, bf16x8& f1)
{
  const int sw = (row & 7) << 4;
  const unsigned short* p = lds + row * 64;
  f0 = *(const bf16x8*)(p + (((quad * 16) ^ sw) >> 1));
  f1 = *(const bf16x8*)(p + (((64 + quad * 16) ^ sw) >> 1));
}

// ---------------------------------------------------------------------------
// fp32 -> bf16 converts (fallback path kernels)
// ---------------------------------------------------------------------------
__global__ __launch_bounds__(256) void cvt_a(const float* __restrict__ s,
                                             unsigned short* __restrict__ d)
{
  int i = blockIdx.x * 256 + threadIdx.x;          // float4 index
  float4 v = ((const float4*)s)[i];
  us4 o = { f2bf(v.x), f2bf(v.y), f2bf(v.z), f2bf(v.w) };
  *(us4*)(d + (size_t)i * 4) = o;
}

__global__ __launch_bounds__(256) void cvt_w(const float* __restrict__ w0,
                                             const float* __restrict__ w1,
                                             const float* __restrict__ w2,
                                             const float* __restrict__ w3,
                                             unsigned short* __restrict__ dst)
{
  const float* s = (blockIdx.y == 0) ? w0 : (blockIdx.y == 1) ? w1
                 : (blockIdx.y == 2) ? w2 : w3;
  unsigned short* d = dst + (size_t)blockIdx.y * 1024 * 1024;
  int i = blockIdx.x * 256 + threadIdx.x;
  float4 v = ((const float4*)s)[i];
  us4 o = { f2bf(v.x), f2bf(v.y), f2bf(v.z), f2bf(v.w) };
  *(us4*)(d + (size_t)i * 4) = o;
}

__global__ __launch_bounds__(256) void pad_cvt(const int* __restrict__ pad,
                                               float* __restrict__ padf)
{
  int i = (blockIdx.x * 256 + threadIdx.x) * 4;
  int4 pv = *(const int4*)(pad + i);
  float4 o = { pv.x ? 0.f : -1e30f, pv.y ? 0.f : -1e30f,
               pv.z ? 0.f : -1e30f, pv.w ? 0.f : -1e30f };
  *(float4*)(padf + i) = o;
}

// ---------------------------------------------------------------------------
// merged converts: qkv (24576 WGs) + weights (4096 WGs) + pad (8 WGs)
// ---------------------------------------------------------------------------
__global__ __launch_bounds__(256) void cvt_all(
    const float* __restrict__ q, const float* __restrict__ k,
    const float* __restrict__ v,
    const float* __restrict__ w0, const float* __restrict__ w1,
    const float* __restrict__ w2, const float* __restrict__ w3,
    const int* __restrict__ pad,
    unsigned short* __restrict__ Ac3, unsigned short* __restrict__ Wall,
    float* __restrict__ padf)
{
  const int bx = blockIdx.x;
  if (bx < 24576) {
    const int y = bx >> 13;                       // 0..2
    const int i = (bx & 8191) * 256 + threadIdx.x;
    const float* s = (y == 0) ? q : (y == 1) ? k : v;
    unsigned short* d = Ac3 + (size_t)y * (B_ * (size_t)SD_);
    float4 x = ((const float4*)s)[i];
    us4 o = { f2bf(x.x), f2bf(x.y), f2bf(x.z), f2bf(x.w) };
    *(us4*)(d + (size_t)i * 4) = o;
  } else if (bx < 24576 + 4096) {
    const int bw = bx - 24576;
    const int y = bw >> 10;                       // 0..3
    const int i = (bw & 1023) * 256 + threadIdx.x;
    const float* s = (y == 0) ? w0 : (y == 1) ? w1 : (y == 2) ? w2 : w3;
    unsigned short* d = Wall + (size_t)y * 1024 * 1024;
    float4 x = ((const float4*)s)[i];
    us4 o = { f2bf(x.x), f2bf(x.y), f2bf(x.z), f2bf(x.w) };
    *(us4*)(d + (size_t)i * 4) = o;
  } else {
    const int i = ((bx - 28672) * 256 + threadIdx.x) * 4;   // 8192 ints total
    int4 pv = *(const int4*)(pad + i);
    float4 o = { pv.x ? 0.f : -1e30f, pv.y ? 0.f : -1e30f,
                 pv.z ? 0.f : -1e30f, pv.w ? 0.f : -1e30f };
    *(float4*)(padf + i) = o;
  }
}

// bijective XCD swizzle over the (x,y) grid plane: nwg = 512 (%8==0).
// bid&7 lands blocks with 8 consecutive m0-tiles (all n0) on one XCD.
__device__ __forceinline__ void xcd_coords(int& n0, int& m0)
{
  const int nwgx = gridDim.x;
  const int nwg  = nwgx * gridDim.y;
  const int bid  = blockIdx.y * nwgx + blockIdx.x;
  const int sw   = (bid & 7) * (nwg >> 3) + (bid >> 3);
  n0 = (sw % nwgx) * 128;
  m0 = (sw / nwgx) * 128;
}

// shared GEMM epilogue: C-layout col=l16, row=quad*4+reg (m89-verified)
__device__ __forceinline__ void gemm_epilogue(
    f32x4 (&acc)[4][4], const float* __restrict__ bias,
    unsigned short* __restrict__ Cb, int n0, int m0,
    int wm, int wn, int l16, int quad)
{
#pragma unroll
  for (int nt = 0; nt < 4; ++nt) {
    const int ncol = n0 + wn * 64 + nt * 16 + l16;
    const float bv = bias[ncol];
#pragma unroll
    for (int mt = 0; mt < 4; ++mt) {
      const int row = m0 + wm * 64 + mt * 16 + quad * 4;
#pragma unroll
      for (int reg = 0; reg < 4; ++reg)
        Cb[(size_t)(row + reg) * 1024 + ncol] = f2bf(acc[mt][nt][reg] + bv);
    }
  }
}

// ---------------------------------------------------------------------------
// bf16 MFMA GEMM body: C[8192,1024] = A @ W^T + bias, bf16 out.
// 128x128 tile, BK=32, 4 waves (2x2), double-buffered, 1 barrier / K-step.
// ROUND-6: SWIZZLED LDS TILE LAYOUT. The old [row][32] layout's frag reads
// (ds_read_b128, 16 rows x 4 quads) put 8 lanes/phase on one bank-quad
// (8-way conflict, 2.94x per op — 6.29M conflicts measured in round 5).
// New layout: rows paired into 128B lines; 16B chunk (row,c) stored at slot
//   s = ((c<<1)|(row&1)) ^ ((row>>1)&7)   within line (row>>1).
// Frag reads then hit each bank-quad with exactly 2 lanes/phase (free, m136).
// gload_lds writes linearly, so the permutation is applied on the SOURCE
// address (rule #21); the read-side swizzle term is per-thread constant.
// ---------------------------------------------------------------------------
__device__ __forceinline__ void gemm_body(
    const unsigned short* __restrict__ A,    // [8192,1024] bf16
    const unsigned short* __restrict__ Wb,   // [1024,1024] bf16, row n = out col
    const float* __restrict__ bias,
    unsigned short* __restrict__ Cb,
    int n0, int m0)
{
  __shared__ unsigned short As[2][4096];   // 2 x 8 KB
  __shared__ unsigned short Bs[2][4096];   // 2 x 8 KB

  const int tid  = threadIdx.x;
  const int lane = tid & 63;
  const int w    = tid >> 6;
  const int wm   = w >> 1, wn = w & 1;
  const int l16  = lane & 15, quad = lane >> 4;

  f32x4 acc[4][4];
#pragma unroll
  for (int mt = 0; mt < 4; ++mt)
#pragma unroll
    for (int nt = 0; nt < 4; ++nt) acc[mt][nt] = (f32x4){0.f, 0.f, 0.f, 0.f};

  // stage decode: LDS chunk cidx -> (row, c). cidx+256 => row+64, same c.
  const int L0   = tid >> 3;
  const int s0d  = (tid & 7) ^ (L0 & 7);
  const int srw  = (L0 << 1) | (s0d & 1);        // source row 0..127
  const int sc   = (s0d >> 1) * 8;               // source elem offset (chunk*8)

  const unsigned short* A0 = A  + (size_t)(m0 + srw) * 1024 + sc;
  const unsigned short* A1 = A  + (size_t)(m0 + srw + 64) * 1024 + sc;
  const unsigned short* B0 = Wb + (size_t)(n0 + srw) * 1024 + sc;
  const unsigned short* B1 = Wb + (size_t)(n0 + srw + 64) * 1024 + sc;
  unsigned short* dA = &As[0][tid * 8];          // +2048 for second chunk
  unsigned short* dB = &Bs[0][tid * 8];

  auto STAGE = [&](int buf, int ko) {
    const int bo = buf * 4096;
    gload16(A0 + ko, dA + bo);
    gload16(A1 + ko, dA + bo + 2048);
    gload16(B0 + ko, dB + bo);
    gload16(B1 + ko, dB + bo + 2048);
  };

  // frag-read addressing: R = base + mt*16 + l16 ->
  //   ushort = (R>>1)*64 + (((quad<<1)|(R&1)) ^ ((R>>1)&7))*8
  // (R>>1)&7 == l16>>1 (bases are multiples of 16) -> swizzle term constant.
  const int swz   = ((((quad << 1) | (l16 & 1)) ^ (l16 >> 1)) << 3);
  const int rbA   = (wm * 32 + (l16 >> 1)) * 64 + swz;
  const int rbB   = (wn * 32 + (l16 >> 1)) * 64 + swz;

  STAGE(0, 0);
  int buf = 0;
  for (int kt = 0; kt < 32; ++kt) {
    __syncthreads();   // tile kt landed (vmcnt drain); prev reads of buf^1 done

    if (kt < 31) STAGE(buf ^ 1, (kt + 1) * 32);   // latency hides under compute

    const unsigned short* Ab = As[buf];
    const unsigned short* Bb = Bs[buf];
    bf16x8 af[4], bfr[4];
#pragma unroll
    for (int mt = 0; mt < 4; ++mt)
      af[mt] = *(const bf16x8*)&Ab[rbA + mt * 512];
#pragma unroll
    for (int nt = 0; nt < 4; ++nt)
      bfr[nt] = *(const bf16x8*)&Bb[rbB + nt * 512];
#pragma unroll
    for (int mt = 0; mt < 4; ++mt)
#pragma unroll
      for (int nt = 0; nt < 4; ++nt)
        acc[mt][nt] = __builtin_amdgcn_mfma_f32_16x16x32_bf16(
            af[mt], bfr[nt], acc[mt][nt], 0, 0, 0);

    buf ^= 1;
  }

  gemm_epilogue(acc, bias, Cb, n0, m0, wm, wn, l16, quad);
}

__global__ __launch_bounds__(256) void gemm_mfma(
    const unsigned short* __restrict__ A, const unsigned short* __restrict__ Wb,
    const float* __restrict__ bias, unsigned short* __restrict__ Cb)
{
  int n0, m0;
  xcd_coords(n0, m0);
  gemm_body(A, Wb, bias, Cb, n0, m0);
}

// batched QKV projection: blockIdx.z selects {q,k,v}
__global__ __launch_bounds__(256) void gemm_qkv(
    const unsigned short* __restrict__ A3,   // 3x [8192,1024] bf16
    const unsigned short* __restrict__ Wall, // 4x [1024,1024] bf16
    const float* __restrict__ bq, const float* __restrict__ bk,
    const float* __restrict__ bv,
    unsigned short* __restrict__ Qb, unsigned short* __restrict__ Kb,
    unsigned short* __restrict__ Vb)
{
  const int z = blockIdx.z;
  const unsigned short* A  = A3 + (size_t)z * (B_ * (size_t)SD_);
  const unsigned short* Wb = Wall + (size_t)z * 1024 * 1024;
  const float* bias = (z == 0) ? bq : (z == 1) ? bk : bv;
  unsigned short* Cb = (z == 0) ? Qb : (z == 1) ? Kb : Vb;
  int n0, m0;
  xcd_coords(n0, m0);
  gemm_body(A, Wb, bias, Cb, n0, m0);
}

// ---------------------------------------------------------------------------
// V transpose: Vt[bh][d][s] = Vflat[bh*131072 + s*64 + d]
// ---------------------------------------------------------------------------
__global__ __launch_bounds__(256) void vtrans(
    const unsigned short* __restrict__ V, unsigned short* __restrict__ Vt)
{
  __shared__ unsigned short t[64][72];   // t[s][d], padded rows
  const int tid = threadIdx.x;
  const int st  = blockIdx.x;            // s-tile 0..31
  const int bh  = blockIdx.y;            // 0..63
  const unsigned short* src = V + (size_t)bh * SHD_ + (size_t)st * 4096;

#pragma unroll
  for (int u = tid; u < 512; u += 256) {           // 512 us8 chunks = 8 KB
    us8 vv = ((const us8*)src)[u];
    int s  = u >> 3;
    int dg = (u & 7) * 8;
    *(us8*)&t[s][dg] = vv;
  }
  __syncthreads();

  unsigned short* dst = Vt + (size_t)bh * SHD_ + st * 64;
#pragma unroll
  for (int u = tid; u < 1024; u += 256) {          // 64 d-rows x 16 us4 chunks
    int d  = u >> 4;
    int s4 = (u & 15) * 4;
    us4 o = { t[s4][d], t[s4 + 1][d], t[s4 + 2][d], t[s4 + 3][d] };
    *(us4*)(dst + (size_t)d * 2048 + s4) = o;
  }
}

// ---------------------------------------------------------------------------
// MFMA flash attention (round-5 version, kept): diagonal pairing + LDS-staged
// K/V + swapped-QK softmax + XCD-pinned bh mapping + defer-rescale (T13).
// ---------------------------------------------------------------------------
__global__ __launch_bounds__(256, 4) void attn_mfma(
    unsigned short* __restrict__ Qb, const unsigned short* __restrict__ Kb,
    const unsigned short* __restrict__ Vt, const float* __restrict__ padf)
{
  __shared__ unsigned short Ks[64 * 64];        // 8 KB, single-buffered
  __shared__ unsigned short Vs[2][64 * 64];     // 16 KB, double-buffered
  __shared__ unsigned short Ps[4][16][72];      // per-wave P strip, 9 KB

  const int tid  = threadIdx.x;
  const int lane = tid & 63;
  const int w    = tid >> 6;
  const int id   = blockIdx.y * 16 + blockIdx.x;
  const int p    = id >> 6;                          // 0..15
  const int bh   = (id & 7) + 8 * ((id >> 3) & 7);   // 0..63, xcd = bh&7
  const int b    = bh >> 4;
  const size_t base = (size_t)bh * SHD_;

  const int l16  = lane & 15;
  const int quad = lane >> 4;

  for (int half = 0; half < 2; ++half) {
    const int it = half ? (31 - p) : p;

    bf16x8 qfrag[2];   // Q rows w*16+l16 -> B operand (columns q)
    {
      const unsigned short* qrow = Qb + base + (size_t)(it * 64 + w * 16 + l16) * 64;
      qfrag[0] = *(const bf16x8*)(qrow + quad * 8);
      qfrag[1] = *(const bf16x8*)(qrow + 32 + quad * 8);
    }

    f32x4 oacc[4];
#pragma unroll
    for (int dt = 0; dt < 4; ++dt) oacc[dt] = (f32x4){0.f, 0.f, 0.f, 0.f};
    float mS = -INFINITY, lS = 0.f;   // softmax state for q = it*64+w*16+l16

    // ---- half prologue: protect LDS from previous half, stage tile 0 ----
    __syncthreads();
    stage_swz(Kb + base, 64, Ks, tid);
    stage_swz(Vt + base, 2048, Vs[0], tid);
    float4 pf[4];
#pragma unroll
    for (int ct = 0; ct < 4; ++ct)
      pf[ct] = *(const float4*)(padf + b * S_ + ct * 16 + quad * 4);
    int cur = 0;

    for (int jt = 0; jt <= it; ++jt) {
      __syncthreads();   // barrier-1: staged K/V(jt) landed (vmcnt drain)

      // ---- QK^T swapped: A = K rows (ct tiles), B = Q ----
      f32x4 sacc[4];
#pragma unroll
      for (int ct = 0; ct < 4; ++ct) {
        bf16x8 k0, k1;
        read_frag_pair(Ks, ct * 16 + l16, quad, k0, k1);
        f32x4 s = (f32x4){0.f, 0.f, 0.f, 0.f};
        s = __builtin_amdgcn_mfma_f32_16x16x32_bf16(k0, qfrag[0], s, 0, 0, 0);
        s = __builtin_amdgcn_mfma_f32_16x16x32_bf16(k1, qfrag[1], s, 0, 0, 0);
        sacc[ct] = s;   // D[k=quad*4+reg (+ct*16)][q=l16]
      }

      // ---- barrier-2 + next-tile stage (hides under softmax+PV) ----
      float4 pfn[4];
      if (jt < it) {
        __syncthreads();   // all waves' K ds_reads complete -> Ks reusable
        stage_swz(Kb + base + (size_t)(jt + 1) * 4096, 64, Ks, tid);
        stage_swz(Vt + base + (jt + 1) * 64, 2048, Vs[cur ^ 1], tid);
#pragma unroll
        for (int ct = 0; ct < 4; ++ct)
          pfn[ct] = *(const float4*)(padf + b * S_ + (jt + 1) * 64 + ct * 16 + quad * 4);
      }

      // ---- swapped softmax: per-lane reduce over 16 regs + 2 shfl_xor ----
      float lg[4][4];
      float mx = -INFINITY;
#pragma unroll
      for (int ct = 0; ct < 4; ++ct)
#pragma unroll
        for (int reg = 0; reg < 4; ++reg) {
          float sc = fmaf(sacc[ct][reg], 0.125f, ((const float*)&pf[ct])[reg]);
          if (jt == it) {   // causal only needed on the diagonal tile
            bool ok = (ct * 16 + quad * 4 + reg) <= (w * 16 + l16);
            sc = ok ? sc : -1e30f;
          }
          lg[ct][reg] = sc;
          mx = fmaxf(mx, sc);
        }
      mx = fmaxf(mx, __shfl_xor(mx, 16, 64));
      mx = fmaxf(mx, __shfl_xor(mx, 32, 64));

      // ---- T13 defer-rescale: only rescale when the max actually grows ----
      if (!__all(mx <= mS + 8.f)) {
        const float mnew = fmaxf(mS, mx);
        const float a    = __expf(mS - mnew);
        mS = mnew;
        lS *= a;
        float aO[4];
#pragma unroll
        for (int reg = 0; reg < 4; ++reg) aO[reg] = __shfl(a, quad * 4 + reg, 64);
#pragma unroll
        for (int dt = 0; dt < 4; ++dt)
#pragma unroll
          for (int reg = 0; reg < 4; ++reg) oacc[dt][reg] *= aO[reg];
      }

      float sm = 0.f;
#pragma unroll
      for (int ct = 0; ct < 4; ++ct) {
        us4 pk;
#pragma unroll
        for (int reg = 0; reg < 4; ++reg) {
          float pe = __expf(lg[ct][reg] - mS);
          sm += pe;
          pk[reg] = f2bf(pe);
        }
        *(us4*)&Ps[w][l16][ct * 16 + quad * 4] = pk;   // P[q=l16][k contig]
      }
      sm += __shfl_xor(sm, 16, 64);
      sm += __shfl_xor(sm, 32, 64);
      lS += sm;

      // ---- PV: A-frag = P rows (LDS strip), B-frags = V^T rows from LDS ----
      bf16x8 pfrag0 = *(const bf16x8*)&Ps[w][l16][quad * 8];
      bf16x8 pfrag1 = *(const bf16x8*)&Ps[w][l16][32 + quad * 8];
#pragma unroll
      for (int dt = 0; dt < 4; ++dt) {
        bf16x8 v0, v1;
        read_frag_pair(Vs[cur], dt * 16 + l16, quad, v0, v1);
        oacc[dt] = __builtin_amdgcn_mfma_f32_16x16x32_bf16(pfrag0, v0, oacc[dt], 0, 0, 0);
        oacc[dt] = __builtin_amdgcn_mfma_f32_16x16x32_bf16(pfrag1, v1, oacc[dt], 0, 0, 0);
      }

      if (jt < it) {
#pragma unroll
        for (int ct = 0; ct < 4; ++ct) pf[ct] = pfn[ct];
        cur ^= 1;
      }
    }

    // epilogue: l back to O layout, normalize, write bf16 in place over Qb
    float lO[4];
#pragma unroll
    for (int reg = 0; reg < 4; ++reg) lO[reg] = __shfl(lS, quad * 4 + reg, 64);
#pragma unroll
    for (int reg = 0; reg < 4; ++reg) {
      const float rl = 1.0f / lO[reg];
      unsigned short* orow = Qb + base + (size_t)(it * 64 + w * 16 + quad * 4 + reg) * 64;
#pragma unroll
      for (int dt = 0; dt < 4; ++dt)
        orow[dt * 16 + l16] = f2bf(oacc[dt][reg] * rl);
    }
  }
}

// ---------------------------------------------------------------------------
// Residual + LayerNorm; O is bf16.
// ---------------------------------------------------------------------------
__global__ __launch_bounds__(256) void ln_kernel(
    const float* __restrict__ x, const unsigned short* __restrict__ O,
    const float* __restrict__ gamma, const float* __restrict__ beta,
    float* __restrict__ out)
{
  __shared__ float red[8];
  const int row = blockIdx.x;
  const int tid = threadIdx.x;
  float4 xv = ((const float4*)x)[(size_t)row * 256 + tid];
  us4 ov4 = *(const us4*)(O + (size_t)row * 1024 + tid * 4);
  float4 y = make_float4(xv.x + bf2f(ov4[0]), xv.y + bf2f(ov4[1]),
                         xv.z + bf2f(ov4[2]), xv.w + bf2f(ov4[3]));
  float s1 = y.x + y.y + y.z + y.w;
  float s2 = y.x*y.x + y.y*y.y + y.z*y.z + y.w*y.w;
#pragma unroll
  for (int off = 32; off >= 1; off >>= 1) {
    s1 += __shfl_xor(s1, off, 64);
    s2 += __shfl_xor(s2, off, 64);
  }
  if ((tid & 63) == 0) { red[tid >> 6] = s1; red[4 + (tid >> 6)] = s2; }
  __syncthreads();
  s1 = red[0] + red[1] + red[2] + red[3];
  s2 = red[4] + red[5] + red[6] + red[7];
  const float mean = s1 * (1.0f / 1024.0f);
  const float var  = fmaxf(s2 * (1.0f / 1024.0f) - mean * mean, 0.f);
  const float rstd = 1.0f / (sqrtf(var) + 1e-8f);
  float4 gv = ((const float4*)gamma)[tid];
  float4 bv = ((const float4*)beta)[tid];
  float4 r;
  r.x = gv.x * (y.x - mean) * rstd + bv.x;
  r.y = gv.y * (y.y - mean) * rstd + bv.y;
  r.z = gv.z * (y.z - mean) * rstd + bv.z;
  r.w = gv.w * (y.w - mean) * rstd + bv.w;
  ((float4*)out)[(size_t)row * 256 + tid] = r;
}

// ---------------------------------------------------------------------------
extern "C" void kernel_launch(void* const* d_in, const int* in_sizes, int n_in,
                              void* d_out, int out_size, void* d_ws, size_t ws_size,
                              hipStream_t stream)
{
  const float* q  = (const float*)d_in[0];
  const float* k  = (const float*)d_in[1];
  const float* v  = (const float*)d_in[2];
  // d_in[3] = causal tril mask — applied analytically (j<=i)
  const int*   pad = (const int*)d_in[4];
  const float* Wq = (const float*)d_in[5];
  const float* bq = (const float*)d_in[6];
  const float* Wk = (const float*)d_in[7];
  const float* bk = (const float*)d_in[8];
  const float* Wv = (const float*)d_in[9];
  const float* bv = (const float*)d_in[10];
  const float* Wo = (const float*)d_in[11];
  const float* bo = (const float*)d_in[12];
  const float* gamma = (const float*)d_in[13];
  const float* beta  = (const float*)d_in[14];
  float* out = (float*)d_out;

  char* ws = (char*)d_ws;
  const size_t MB = 1024 * 1024;
  dim3 gg(8, 64), bb(256);

  if (ws_size >= 121 * MB) {
    // ---- batched layout: 120 MB + padf ----
    unsigned short* Ac3  = (unsigned short*)(ws);             // 48 MB (q,k,v bf16)
    unsigned short* Qb   = (unsigned short*)(ws + 48 * MB);
    unsigned short* Kb   = (unsigned short*)(ws + 64 * MB);
    unsigned short* Vb   = (unsigned short*)(ws + 80 * MB);
    unsigned short* Vtb  = (unsigned short*)(ws + 96 * MB);
    unsigned short* Wall = (unsigned short*)(ws + 112 * MB);  // 8 MB
    float*          padf = (float*)(ws + 120 * MB);           // 32 KB
    unsigned short* Obuf = Ac3;                               // alias: dead after V-GEMM

    cvt_all<<<dim3(28680), 256, 0, stream>>>(q, k, v, Wq, Wk, Wv, Wo, pad,
                                             Ac3, Wall, padf);
    gemm_qkv<<<dim3(8, 64, 3), bb, 0, stream>>>(Ac3, Wall, bq, bk, bv, Qb, Kb, Vb);
    vtrans<<<dim3(32, 64), 256, 0, stream>>>(Vb, Vtb);
    attn_mfma<<<dim3(16, 64), 256, 0, stream>>>(Qb, Kb, Vtb, padf);
    gemm_mfma<<<gg, bb, 0, stream>>>(Qb, Wall + 3 * MB, bo, Obuf);
    ln_kernel<<<dim3(B_ * S_), 256, 0, stream>>>(q, Obuf, gamma, beta, out);
  } else {
    // ---- sequential fallback (88 MB + padf) ----
    unsigned short* Ac   = (unsigned short*)(ws);
    unsigned short* Qb   = (unsigned short*)(ws + 16 * MB);
    unsigned short* Kb   = (unsigned short*)(ws + 32 * MB);
    unsigned short* Vb   = (unsigned short*)(ws + 48 * MB);
    unsigned short* Vtb  = (unsigned short*)(ws + 64 * MB);
    unsigned short* Wall = (unsigned short*)(ws + 80 * MB);
    float*          padf = (float*)(ws + 88 * MB);
    unsigned short* Obuf = Ac;

    cvt_w<<<dim3(1024, 4), 256, 0, stream>>>(Wq, Wk, Wv, Wo, Wall);
    pad_cvt<<<8, 256, 0, stream>>>(pad, padf);
    cvt_a<<<8192, 256, 0, stream>>>(q, Ac);
    gemm_mfma<<<gg, bb, 0, stream>>>(Ac, Wall + 0 * MB, bq, Qb);
    cvt_a<<<8192, 256, 0, stream>>>(k, Ac);
    gemm_mfma<<<gg, bb, 0, stream>>>(Ac, Wall + 1 * MB, bk, Kb);
    cvt_a<<<8192, 256, 0, stream>>>(v, Ac);
    gemm_mfma<<<gg, bb, 0, stream>>>(Ac, Wall + 2 * MB, bv, Vb);
    vtrans<<<dim3(32, 64), 256, 0, stream>>>(Vb, Vtb);
    attn_mfma<<<dim3(16, 64), 256, 0, stream>>>(Qb, Kb, Vtb, padf);
    gemm_mfma<<<gg, bb, 0, stream>>>(Qb, Wall + 3 * MB, bo, Obuf);
    ln_kernel<<<dim3(B_ * S_), 256, 0, stream>>>(q, Obuf, gamma, beta, out);
  }
}